// Round 4
// baseline (122.566 us; speedup 1.0000x reference)
//
#include <hip/hip_runtime.h>

typedef unsigned short u16;
typedef __attribute__((ext_vector_type(8))) short short8;
typedef __attribute__((ext_vector_type(4))) float f32x4;

#define X0    (-6.0f)
#define GH    (12.0f / 256.0f)     // grid spacing h = 0.046875
#define LOG2E 1.44269504089f

// gfx950 hardware packed f32->bf16 (RNE), no builtin -- inline asm per guide T12.
__device__ __forceinline__ unsigned int cvtpk(float lo, float hi) {
    unsigned int r;
    asm("v_cvt_pk_bf16_f32 %0, %1, %2" : "=v"(r) : "v"(lo), "v"(hi));
    return r;
}
__device__ __forceinline__ uint4 cvt8u(float4 lo, float4 hi) {
    return make_uint4(cvtpk(lo.x, lo.y), cvtpk(lo.z, lo.w),
                      cvtpk(hi.x, hi.y), cvtpk(hi.z, hi.w));
}
__device__ __forceinline__ u16 f2bf(float x) {   // single value via HW RNE
    return (u16)(cvtpk(x, x) & 0xffffu);
}
__device__ __forceinline__ float bf2f_lo(unsigned int u) {
    union { unsigned int x; float f; } v; v.x = u << 16; return v.f;
}
__device__ __forceinline__ float bf2f_hi(unsigned int u) {
    union { unsigned int x; float f; } v; v.x = u & 0xffff0000u; return v.f;
}
__device__ __forceinline__ void glds16(const float* g, const float* l) {
    __builtin_amdgcn_global_load_lds(
        (const __attribute__((address_space(1))) void*)g,
        (__attribute__((address_space(3))) void*)l, 16, 0, 0);
}

// K0: W[(b*8+ks)][J=0..255][s=0..511] = bf16 tent(J - t(key)).  8 MB, built
// ONCE -- removes the 16x-redundant per-v-block B-fragment rebuild in K1.
// Same arithmetic as the old in-K1 build: u, floor, clamp, t=j+f,
// w = max(0, 1-|J-t|), RNE pack => bit-identical Hpart.
__global__ __launch_bounds__(256) void wbuild_kernel(
    const float* __restrict__ key, u16* __restrict__ W)
{
    const int gid = blockIdx.x * 256 + threadIdx.x;  // 524288 total
    const int sg  = gid & 63;                        // 8-wide s-group
    const int J   = (gid >> 6) & 255;
    const int pk_ = gid >> 14;                       // b*8+ks (0..31)
    const float* kp = key + pk_ * 512 + sg * 8;      // b*4096+ks*512+s
    const float Jf = (float)J;
    float w[8];
    #pragma unroll
    for (int i = 0; i < 8; ++i) {
        float k = kp[i];
        float u = (k - X0) * (256.0f / 12.0f);
        int j = (int)floorf(u);
        j = j < 0 ? 0 : (j > 254 ? 254 : j);
        float f = u - (float)j;
        f = f < 0.0f ? 0.0f : (f > 1.0f ? 1.0f : f);
        float t = (float)j + f;
        float d = 1.0f - fabsf(Jf - t);
        w[i] = d > 0.0f ? d : 0.0f;
    }
    *(uint4*)(W + ((size_t)(pk_ * 256 + J) << 9) + sg * 8) =
        cvt8u(make_float4(w[0], w[1], w[2], w[3]),
              make_float4(w[4], w[5], w[6], w[7]));
}

// K1: Hpart[b][ks][v][j] = bf16( sum_{s in chunk} value[v][s] * W[s][j] ).
// M=32 v-rows/block, N=256 j, K-chunk=512 s. Full 64 KB A-tile prefetched
// (16 glds16 in flight, ONE barrier). B-fragments now ONE dwordx4 load each
// from the precomputed W plane (L2-resident, 64B-contiguous per 4 lanes).
__global__ __launch_bounds__(256) void hpart_kernel(
    const float* __restrict__ value, const u16* __restrict__ W,
    u16* __restrict__ Hpart)
{
    __shared__ float Vt[16 * 1024];   // 64 KB, [kk][row][32 f32], chunk-swizzled

    const int tid   = threadIdx.x;
    const int v0    = blockIdx.x << 5;    // 0..480
    const int b     = blockIdx.y;
    const int ks    = blockIdx.z;
    const int kbase = ks << 9;            // 512-wide s chunk
    const int lane  = tid & 63;
    const int wave  = tid >> 6;
    const int wj    = wave << 6;          // wave owns 64 j
    const int m15   = lane & 15;
    const int kq    = lane >> 4;

    // issue ALL 16 tile-loads (16B swizzle on the global source, LDS linear)
    const int srow = tid >> 3;                   // 0..31
    const int scs  = (tid & 7) ^ (srow & 7);     // swizzled 16B chunk
    const float* gsrc = value + (size_t)(b * 512 + v0 + srow) * 4096 + kbase
                              + (scs << 2);
    const float* ldst = Vt + (srow << 5) + ((tid & 7) << 2);
    #pragma unroll
    for (int kk = 0; kk < 16; ++kk)
        glds16(gsrc + (kk << 5), ldst + (kk << 10));

    // W rows for this wave's 4 J-groups (plane for (b,ks))
    const u16* Wp = W + ((size_t)(b * 8 + ks) << 17);   // 256*512 u16
    const u16* wrow[4];
    #pragma unroll
    for (int ni = 0; ni < 4; ++ni)
        wrow[ni] = Wp + ((size_t)(wj + ni * 16 + m15) << 9) + (kq << 3);

    f32x4 acc[2][4];
    #pragma unroll
    for (int i = 0; i < 2; ++i)
        #pragma unroll
        for (int j = 0; j < 4; ++j)
            acc[i][j] = (f32x4){0.f, 0.f, 0.f, 0.f};

    __syncthreads();     // drains all 16 glds; only barrier in K1

    for (int kk = 0; kk < 16; ++kk) {
        const float* Vk = Vt + (kk << 10);

        union U { short8 s; uint4 u; } af[2];
        #pragma unroll
        for (int mi = 0; mi < 2; ++mi) {
            int m  = mi * 16 + m15;
            int c0 = ((2 * kq)     ^ (m & 7)) << 2;
            int c1 = ((2 * kq + 1) ^ (m & 7)) << 2;
            float4 lo = *(const float4*)(Vk + (m << 5) + c0);
            float4 hi = *(const float4*)(Vk + (m << 5) + c1);
            af[mi].u = cvt8u(lo, hi);
        }

        #pragma unroll
        for (int ni = 0; ni < 4; ++ni) {
            short8 bf = *(const short8*)(wrow[ni] + (kk << 5));
            #pragma unroll
            for (int mi = 0; mi < 2; ++mi)
                acc[mi][ni] = __builtin_amdgcn_mfma_f32_16x16x32_bf16(
                    af[mi].s, bf, acc[mi][ni], 0, 0, 0);
        }
    }

    // private-plane epilogue: bf16 scalar stores, no atomics
    #pragma unroll
    for (int mi = 0; mi < 2; ++mi)
        #pragma unroll
        for (int ni = 0; ni < 4; ++ni) {
            #pragma unroll
            for (int r = 0; r < 4; ++r) {
                int v = v0 + mi * 16 + (kq << 2) + r;      // row = quad*4+reg
                Hpart[((size_t)(b * 8 + ks) * 512 + v) * 256
                      + wj + ni * 16 + m15] = f2bf(acc[mi][ni][r]);
            }
        }
}

// K2: Hbf[b][v][j] = bf16( sum_{ks<8} Hpart[b][ks][v][j] ). Streaming, 9 MB.
__global__ __launch_bounds__(256) void hred_kernel(
    const u16* __restrict__ Hpart, u16* __restrict__ Hbf)
{
    const int gid  = blockIdx.x * 256 + threadIdx.x;   // 0..65535
    const int b    = gid >> 14;
    const size_t off8 = (size_t)(gid & 16383) * 8;     // 8 u16 per thread
    float s[8];
    #pragma unroll
    for (int i = 0; i < 8; ++i) s[i] = 0.f;
    #pragma unroll
    for (int ks = 0; ks < 8; ++ks) {
        const u16* p = Hpart + (size_t)(b * 8 + ks) * 131072 + off8;
        uint4 a = *(const uint4*)p;                    // 8 bf16
        s[0] += bf2f_lo(a.x); s[1] += bf2f_hi(a.x);
        s[2] += bf2f_lo(a.y); s[3] += bf2f_hi(a.y);
        s[4] += bf2f_lo(a.z); s[5] += bf2f_hi(a.z);
        s[6] += bf2f_lo(a.w); s[7] += bf2f_hi(a.w);
    }
    *(uint4*)(Hbf + (size_t)b * 131072 + off8) =
        cvt8u(make_float4(s[0], s[1], s[2], s[3]),
              make_float4(s[4], s[5], s[6], s[7]));
}

// K3: out[b][t][v] = sum_k G(q_t, x_k) * H[v][k].
// Whole H-tile (128 v x 256 k bf16) staged ONCE -> single barrier, then
// 8 barrier-free MFMA steps. Gaussian row built INCREMENTALLY:
//   e_{j+1} = e_j * r_j,  r_{j+1} = r_j * rho,  rho = 2^(2*c2*h^2)
__global__ __launch_bounds__(256) void gemm_kernel(
    const float* __restrict__ query, const float* __restrict__ log_scale,
    const u16* __restrict__ Hbf, float* __restrict__ out)
{
    extern __shared__ u16 Hl[];        // 128 rows x 264 stride = 67584 B

    const int tid  = threadIdx.x;
    const int v0   = blockIdx.x << 7;
    const int t0   = blockIdx.y << 7;
    const int b    = blockIdx.z;
    const int lane = tid & 63;
    const int wave = tid >> 6;
    const int wv   = (wave & 1) << 6;
    const int wt   = (wave >> 1) << 6;
    const int m15  = lane & 15;
    const int kq   = lane >> 4;

    const float c2   = -0.5f * LOG2E * exp2f(-2.0f * LOG2E * log_scale[0]);
    const float rho  = exp2f(2.0f * c2 * GH * GH);   // ratio-of-ratios
    const float c2h2 = c2 * GH * GH;
    const float A    = 2.0f * c2 * GH;

    float q[4];
    for (int ni = 0; ni < 4; ++ni)
        q[ni] = query[b * 4096 + t0 + wt + ni * 16 + m15];

    // stage: thread = (row = tid>>1, half = tid&1); contiguous 256 B per thread
    {
        const int row = tid >> 1, half = tid & 1;
        const u16* src = Hbf + (size_t)(b * 512 + v0 + row) * 256 + half * 128;
        u16* dst = Hl + row * 264 + half * 128;
        #pragma unroll
        for (int i = 0; i < 16; ++i)
            *(uint4*)(dst + i * 8) = *(const uint4*)(src + i * 8);
    }
    __syncthreads();

    f32x4 acc[4][4];
    for (int i = 0; i < 4; ++i)
        for (int j = 0; j < 4; ++j)
            acc[i][j] = (f32x4){0.f, 0.f, 0.f, 0.f};

    for (int ks = 0; ks < 8; ++ks) {
        const int k0 = ks << 5;
        short8 af[4];
        for (int i = 0; i < 4; ++i)
            af[i] = *(const short8*)(Hl + (wv + i * 16 + m15) * 264 + k0 + kq * 8);

        const float xb = X0 + GH * (float)(k0 + kq * 8);

        short8 bfr[4];
        #pragma unroll
        for (int ni = 0; ni < 4; ++ni) {
            float d0 = q[ni] - xb;
            float e  = exp2f(c2 * d0 * d0);        // w at j=0
            float r  = exp2f(c2h2 - A * d0);       // e_{j+1}/e_j at j=0
            float w[8];
            #pragma unroll
            for (int j = 0; j < 8; ++j) {
                w[j] = e;
                e *= r;
                r *= rho;
            }
            union U { short8 s; uint4 u; } v;
            v.u = cvt8u(make_float4(w[0], w[1], w[2], w[3]),
                        make_float4(w[4], w[5], w[6], w[7]));
            bfr[ni] = v.s;
        }
        for (int mi = 0; mi < 4; ++mi)
            for (int ni = 0; ni < 4; ++ni)
                acc[mi][ni] = __builtin_amdgcn_mfma_f32_16x16x32_bf16(
                    af[mi], bfr[ni], acc[mi][ni], 0, 0, 0);
    }

    for (int mi = 0; mi < 4; ++mi)
        for (int ni = 0; ni < 4; ++ni) {
            int t = t0 + wt + ni * 16 + m15;
            float* o = out + (size_t)(b * 4096 + t) * 512
                           + v0 + wv + mi * 16 + (kq << 2);
            *(f32x4*)o = acc[mi][ni];
        }
}

extern "C" void kernel_launch(void* const* d_in, const int* in_sizes, int n_in,
                              void* d_out, int out_size, void* d_ws, size_t ws_size,
                              hipStream_t stream)
{
    const float* query = (const float*)d_in[0];   // [4,4096,1]
    const float* key   = (const float*)d_in[1];   // [4,4096,1]
    const float* value = (const float*)d_in[2];   // [4,512,4096]
    const float* lsc   = (const float*)d_in[3];   // scalar
    float* out = (float*)d_out;                   // [4,4096,512]

    u16* Hpart = (u16*)d_ws;                                      // 8 MB (bf16)
    u16* Hbf   = (u16*)((char*)d_ws + (size_t)8 * 1024 * 1024);   // 1 MB
    u16* W     = (u16*)((char*)d_ws + (size_t)9 * 1024 * 1024);   // 8 MB (bf16)

    wbuild_kernel<<<2048, 256, 0, stream>>>(key, W);
    hpart_kernel<<<dim3(16, 4, 8), 256, 0, stream>>>(value, W, Hpart);
    hred_kernel<<<256, 256, 0, stream>>>(Hpart, Hbf);
    gemm_kernel<<<dim3(4, 32, 4), 256, 128 * 264 * 2, stream>>>(query, lsc, Hbf, out);
}

// Round 5
// 109.208 us; speedup vs baseline: 1.1223x; 1.1223x over previous
//
#include <hip/hip_runtime.h>

typedef unsigned short u16;
typedef __attribute__((ext_vector_type(8))) short short8;
typedef __attribute__((ext_vector_type(4))) float f32x4;

#define X0    (-6.0f)
#define GH    (12.0f / 256.0f)     // grid spacing h = 0.046875
#define LOG2E 1.44269504089f

// gfx950 hardware packed f32->bf16 (RNE), no builtin -- inline asm per guide T12.
__device__ __forceinline__ unsigned int cvtpk(float lo, float hi) {
    unsigned int r;
    asm("v_cvt_pk_bf16_f32 %0, %1, %2" : "=v"(r) : "v"(lo), "v"(hi));
    return r;
}
__device__ __forceinline__ uint4 cvt8u(float4 lo, float4 hi) {
    return make_uint4(cvtpk(lo.x, lo.y), cvtpk(lo.z, lo.w),
                      cvtpk(hi.x, hi.y), cvtpk(hi.z, hi.w));
}
__device__ __forceinline__ u16 f2bf(float x) {   // single value via HW RNE
    return (u16)(cvtpk(x, x) & 0xffffu);
}
__device__ __forceinline__ float bf2f_lo(unsigned int u) {
    union { unsigned int x; float f; } v; v.x = u << 16; return v.f;
}
__device__ __forceinline__ float bf2f_hi(unsigned int u) {
    union { unsigned int x; float f; } v; v.x = u & 0xffff0000u; return v.f;
}

// K1: Hpart[b][ks][v][j] = bf16( sum_{s in chunk} value[v][s] * W_cic[s][j] ).
// M=32 v-rows/block, N=256 j, K-chunk=512 s, ONE barrier.
// NEW vs r3: (a) V staged as bf16 [kk][32][32] (32 KB, XOR-swizzled 16B
// chunks) -> A-frag is one ds_read_b128, zero per-kk converts.
// (b) B built by SPARSE SCATTER into a wave-private [64 j][32 s] bf16 tile:
// lane s writes (1-f) at row j, f at row j+1 (cols distinct -> no collision),
// all lanes ds_read_b128 their frags, writers re-zero. Same-wave DS ops are
// in-order -> no barrier. Replaces the 112-VALU/kk dense tent build.
// Values are bit-identical to the dense build (same RNE converts).
__global__ __launch_bounds__(256) void hpart_kernel(
    const float* __restrict__ key, const float* __restrict__ value,
    u16* __restrict__ Hpart)
{
    __shared__ u16    Vt[16 * 1024];   // 32 KB  [kk][row 0..31][32 bf16]
    __shared__ float2 jf[512];         // 4 KB   ( (float)j , f )
    __shared__ u16    bt[4][64 * 32];  // 16 KB  wave-private B tiles

    const int tid   = threadIdx.x;
    const int v0    = blockIdx.x << 5;    // 0..480
    const int b     = blockIdx.y;
    const int ks    = blockIdx.z;
    const int kbase = ks << 9;            // 512-wide s chunk
    const int lane  = tid & 63;
    const int wave  = tid >> 6;
    const int wj    = wave << 6;          // wave owns 64 j
    const int m15   = lane & 15;
    const int kq    = lane >> 4;

    // key -> (j, f) LUT
    #pragma unroll
    for (int r = 0; r < 2; ++r) {
        int s = tid + (r << 8);
        float k = key[b * 4096 + kbase + s];
        float u = (k - X0) * (256.0f / 12.0f);
        int j = (int)floorf(u);
        j = j < 0 ? 0 : (j > 254 ? 254 : j);
        float f = u - (float)j;
        f = f < 0.0f ? 0.0f : (f > 1.0f ? 1.0f : f);
        jf[s] = make_float2((float)j, f);
    }

    // stage V as bf16: thread = (row = tid>>3, g = tid&7), 4 f32 per (kk,thread)
    {
        const int row = tid >> 3, g = tid & 7;
        const float* gv = value + (size_t)(b * 512 + v0 + row) * 4096 + kbase
                                + (g << 2);
        float4 ld[16];
        #pragma unroll
        for (int kk = 0; kk < 16; ++kk)
            ld[kk] = *(const float4*)(gv + (kk << 5));
        const int ch = ((g >> 1) ^ ((row >> 1) & 3));   // swizzled 16B chunk
        u16* dst0 = Vt + (row << 5) + (ch << 3) + ((g & 1) << 2);
        #pragma unroll
        for (int kk = 0; kk < 16; ++kk) {
            uint2 w;
            w.x = cvtpk(ld[kk].x, ld[kk].y);
            w.y = cvtpk(ld[kk].z, ld[kk].w);
            *(uint2*)(dst0 + (kk << 10)) = w;
        }
    }

    // zero my wave's B tile (64x32 bf16 = 4 KB)
    u16* myb = bt[wave];
    {
        uint4 z = make_uint4(0u, 0u, 0u, 0u);
        #pragma unroll
        for (int zz = 0; zz < 4; ++zz)
            *(uint4*)(myb + (lane << 5) + (zz << 3)) = z;
    }

    f32x4 acc[2][4];
    #pragma unroll
    for (int i = 0; i < 2; ++i)
        #pragma unroll
        for (int j = 0; j < 4; ++j)
            acc[i][j] = (f32x4){0.f, 0.f, 0.f, 0.f};

    __syncthreads();     // covers jf + Vt + zero-init; only barrier in K1

    const bool wr = (lane < 32);

    for (int kk = 0; kk < 16; ++kk) {
        // A fragments: one ds_read_b128 per mi (already bf16)
        short8 af[2];
        #pragma unroll
        for (int mi = 0; mi < 2; ++mi) {
            int m = mi * 16 + m15;
            af[mi] = *(const short8*)(Vt + (kk << 10) + (m << 5)
                                      + ((kq ^ ((m >> 1) & 3)) << 3));
        }

        // sparse scatter: lane s of each wave writes its 2 tent weights
        int r0 = -1, r1 = -1; int a0, a1; unsigned pkw = 0;
        if (wr) {
            float2 p = jf[(kk << 5) + lane];
            int j   = (int)p.x;
            float f = p.y;
            pkw = cvtpk(1.0f - f, f);        // lo -> row j, hi -> row j+1
            r0 = j - wj; r1 = r0 + 1;
            a0 = (r0 << 5) + (((lane >> 3) ^ ((r0 >> 1) & 3)) << 3) + (lane & 7);
            a1 = (r1 << 5) + (((lane >> 3) ^ ((r1 >> 1) & 3)) << 3) + (lane & 7);
            if (r0 >= 0 && r0 < 64) myb[a0] = (u16)(pkw & 0xffffu);
            if (r1 >= 0 && r1 < 64) myb[a1] = (u16)(pkw >> 16);
        }

        // B fragments + MFMA (same-wave DS in-order: reads see the scatter)
        #pragma unroll
        for (int ni = 0; ni < 4; ++ni) {
            int Jr = ni * 16 + m15;
            short8 bf = *(const short8*)(myb + (Jr << 5)
                                         + ((kq ^ ((Jr >> 1) & 3)) << 3));
            #pragma unroll
            for (int mi = 0; mi < 2; ++mi)
                acc[mi][ni] = __builtin_amdgcn_mfma_f32_16x16x32_bf16(
                    af[mi], bf, acc[mi][ni], 0, 0, 0);
        }

        // undo: restore zeros for next kk (ordered after the reads above)
        if (wr) {
            if (r0 >= 0 && r0 < 64) myb[a0] = 0;
            if (r1 >= 0 && r1 < 64) myb[a1] = 0;
        }
    }

    // private-plane epilogue: bf16 scalar stores, no atomics
    #pragma unroll
    for (int mi = 0; mi < 2; ++mi)
        #pragma unroll
        for (int ni = 0; ni < 4; ++ni) {
            #pragma unroll
            for (int r = 0; r < 4; ++r) {
                int v = v0 + mi * 16 + (kq << 2) + r;      // row = quad*4+reg
                Hpart[((size_t)(b * 8 + ks) * 512 + v) * 256
                      + wj + ni * 16 + m15] = f2bf(acc[mi][ni][r]);
            }
        }
}

// K2: Hbf[b][v][j] = bf16( sum_{ks<8} Hpart[b][ks][v][j] ). Streaming, 9 MB.
__global__ __launch_bounds__(256) void hred_kernel(
    const u16* __restrict__ Hpart, u16* __restrict__ Hbf)
{
    const int gid  = blockIdx.x * 256 + threadIdx.x;   // 0..65535
    const int b    = gid >> 14;
    const size_t off8 = (size_t)(gid & 16383) * 8;     // 8 u16 per thread
    float s[8];
    #pragma unroll
    for (int i = 0; i < 8; ++i) s[i] = 0.f;
    #pragma unroll
    for (int ks = 0; ks < 8; ++ks) {
        const u16* p = Hpart + (size_t)(b * 8 + ks) * 131072 + off8;
        uint4 a = *(const uint4*)p;                    // 8 bf16
        s[0] += bf2f_lo(a.x); s[1] += bf2f_hi(a.x);
        s[2] += bf2f_lo(a.y); s[3] += bf2f_hi(a.y);
        s[4] += bf2f_lo(a.z); s[5] += bf2f_hi(a.z);
        s[6] += bf2f_lo(a.w); s[7] += bf2f_hi(a.w);
    }
    *(uint4*)(Hbf + (size_t)b * 131072 + off8) =
        cvt8u(make_float4(s[0], s[1], s[2], s[3]),
              make_float4(s[4], s[5], s[6], s[7]));
}

// K3: out[b][t][v] = sum_k G(q_t, x_k) * H[v][k].
// Whole H-tile (128 v x 256 k bf16) staged ONCE -> single barrier, then
// 8 barrier-free MFMA steps. Gaussian row built INCREMENTALLY:
//   e_{j+1} = e_j * r_j,  r_{j+1} = r_j * rho,  rho = 2^(2*c2*h^2)
__global__ __launch_bounds__(256) void gemm_kernel(
    const float* __restrict__ query, const float* __restrict__ log_scale,
    const u16* __restrict__ Hbf, float* __restrict__ out)
{
    extern __shared__ u16 Hl[];        // 128 rows x 264 stride = 67584 B

    const int tid  = threadIdx.x;
    const int v0   = blockIdx.x << 7;
    const int t0   = blockIdx.y << 7;
    const int b    = blockIdx.z;
    const int lane = tid & 63;
    const int wave = tid >> 6;
    const int wv   = (wave & 1) << 6;
    const int wt   = (wave >> 1) << 6;
    const int m15  = lane & 15;
    const int kq   = lane >> 4;

    const float c2   = -0.5f * LOG2E * exp2f(-2.0f * LOG2E * log_scale[0]);
    const float rho  = exp2f(2.0f * c2 * GH * GH);   // ratio-of-ratios
    const float c2h2 = c2 * GH * GH;
    const float A    = 2.0f * c2 * GH;

    float q[4];
    for (int ni = 0; ni < 4; ++ni)
        q[ni] = query[b * 4096 + t0 + wt + ni * 16 + m15];

    // stage: thread = (row = tid>>1, half = tid&1); contiguous 256 B per thread
    {
        const int row = tid >> 1, half = tid & 1;
        const u16* src = Hbf + (size_t)(b * 512 + v0 + row) * 256 + half * 128;
        u16* dst = Hl + row * 264 + half * 128;
        #pragma unroll
        for (int i = 0; i < 16; ++i)
            *(uint4*)(dst + i * 8) = *(const uint4*)(src + i * 8);
    }
    __syncthreads();

    f32x4 acc[4][4];
    for (int i = 0; i < 4; ++i)
        for (int j = 0; j < 4; ++j)
            acc[i][j] = (f32x4){0.f, 0.f, 0.f, 0.f};

    for (int ks = 0; ks < 8; ++ks) {
        const int k0 = ks << 5;
        short8 af[4];
        for (int i = 0; i < 4; ++i)
            af[i] = *(const short8*)(Hl + (wv + i * 16 + m15) * 264 + k0 + kq * 8);

        const float xb = X0 + GH * (float)(k0 + kq * 8);

        short8 bfr[4];
        #pragma unroll
        for (int ni = 0; ni < 4; ++ni) {
            float d0 = q[ni] - xb;
            float e  = exp2f(c2 * d0 * d0);        // w at j=0
            float r  = exp2f(c2h2 - A * d0);       // e_{j+1}/e_j at j=0
            float w[8];
            #pragma unroll
            for (int j = 0; j < 8; ++j) {
                w[j] = e;
                e *= r;
                r *= rho;
            }
            union U { short8 s; uint4 u; } v;
            v.u = cvt8u(make_float4(w[0], w[1], w[2], w[3]),
                        make_float4(w[4], w[5], w[6], w[7]));
            bfr[ni] = v.s;
        }
        for (int mi = 0; mi < 4; ++mi)
            for (int ni = 0; ni < 4; ++ni)
                acc[mi][ni] = __builtin_amdgcn_mfma_f32_16x16x32_bf16(
                    af[mi], bfr[ni], acc[mi][ni], 0, 0, 0);
    }

    for (int mi = 0; mi < 4; ++mi)
        for (int ni = 0; ni < 4; ++ni) {
            int t = t0 + wt + ni * 16 + m15;
            float* o = out + (size_t)(b * 4096 + t) * 512
                           + v0 + wv + mi * 16 + (kq << 2);
            *(f32x4*)o = acc[mi][ni];
        }
}

extern "C" void kernel_launch(void* const* d_in, const int* in_sizes, int n_in,
                              void* d_out, int out_size, void* d_ws, size_t ws_size,
                              hipStream_t stream)
{
    const float* query = (const float*)d_in[0];   // [4,4096,1]
    const float* key   = (const float*)d_in[1];   // [4,4096,1]
    const float* value = (const float*)d_in[2];   // [4,512,4096]
    const float* lsc   = (const float*)d_in[3];   // scalar
    float* out = (float*)d_out;                   // [4,4096,512]

    u16* Hpart = (u16*)d_ws;                                      // 8 MB (bf16)
    u16* Hbf   = (u16*)((char*)d_ws + (size_t)8 * 1024 * 1024);   // 1 MB

    hpart_kernel<<<dim3(16, 4, 8), 256, 0, stream>>>(key, value, Hpart);
    hred_kernel<<<256, 256, 0, stream>>>(Hpart, Hbf);
    gemm_kernel<<<dim3(4, 32, 4), 256, 128 * 264 * 2, stream>>>(query, lsc, Hbf, out);
}